// Round 1
// baseline (1376.977 us; speedup 1.0000x reference)
//
#include <hip/hip_runtime.h>
#include <hip/hip_bf16.h>
#include <stdint.h>

typedef unsigned short u16;
typedef __attribute__((ext_vector_type(8))) short short8;
typedef __attribute__((ext_vector_type(4))) float floatx4;

#define BROWS 65536
#define EDIM 512
#define FFDIM 1024

__device__ __forceinline__ u16 f2bf(float f) {
    union { float f; uint32_t u; } v; v.f = f;
    uint32_t r = v.u + 0x7fffu + ((v.u >> 16) & 1u);
    return (u16)(r >> 16);
}
__device__ __forceinline__ float bf2f(u16 h) {
    union { uint32_t u; float f; } v; v.u = ((uint32_t)h) << 16;
    return v.f;
}

// ---------------- fp32 -> bf16 cast (vectorized) ----------------
__global__ __launch_bounds__(256) void cast_kernel(const float* __restrict__ src,
                                                   u16* __restrict__ dst, int n4) {
    int i = blockIdx.x * blockDim.x + threadIdx.x;
    int stride = gridDim.x * blockDim.x;
    for (; i < n4; i += stride) {
        float4 a = ((const float4*)src)[i];
        ushort4 o;
        o.x = f2bf(a.x); o.y = f2bf(a.y); o.z = f2bf(a.z); o.w = f2bf(a.w);
        ((ushort4*)dst)[i] = o;
    }
}

// ---------------- fused attention weight prep: M = Wo @ Wv, beff = Wo@bv + bo ----
__global__ __launch_bounds__(256) void prep_attn(const float* __restrict__ Wv,
                                                 const float* __restrict__ Wo,
                                                 const float* __restrict__ bv,
                                                 const float* __restrict__ bo,
                                                 u16* __restrict__ M,
                                                 float* __restrict__ beff) {
    __shared__ float wo[8][512];
    __shared__ float bvs[512];
    const int n0 = blockIdx.x * 8;
    const int tid = threadIdx.x;
    for (int r = 0; r < 8; ++r)
        for (int j = tid; j < 512; j += 256) wo[r][j] = Wo[(n0 + r) * 512 + j];
    for (int j = tid; j < 512; j += 256) bvs[j] = bv[j];
    __syncthreads();
    float acc0[8] = {}, acc1[8] = {};
    for (int j = 0; j < 512; ++j) {
        float v0 = Wv[j * 512 + tid];
        float v1 = Wv[j * 512 + tid + 256];
        #pragma unroll
        for (int r = 0; r < 8; ++r) { acc0[r] += wo[r][j] * v0; acc1[r] += wo[r][j] * v1; }
    }
    #pragma unroll
    for (int r = 0; r < 8; ++r) {
        M[(n0 + r) * 512 + tid]       = f2bf(acc0[r]);
        M[(n0 + r) * 512 + tid + 256] = f2bf(acc1[r]);
    }
    if (tid < 8) {
        float s = bo[n0 + tid];
        for (int j = 0; j < 512; ++j) s += wo[tid][j] * bvs[j];
        beff[n0 + tid] = s;
    }
}

// ---------------- bf16 GEMM: out = epilogue(A @ W^T + bias) ----------------
// A: [M][K] bf16, W: [N][K] bf16. 128x128 tile, BK=64, 256 threads (4 waves).
// EPI: 0 = GELU(exact) -> bf16 ; 1 = + fp32 residual -> bf16 ; 2 = + bf16 residual -> bf16 (in-place safe)
template <int EPI>
__global__ __launch_bounds__(256, 2) void gemm_bt(const u16* __restrict__ A,
                                                  const u16* __restrict__ W,
                                                  const float* __restrict__ bias,
                                                  int K,
                                                  const float* __restrict__ residf,
                                                  const u16* residb,
                                                  u16* out) {
    __shared__ __align__(16) u16 As[128 * 64];
    __shared__ __align__(16) u16 Bs[128 * 64];
    const int tid = threadIdx.x;
    const int l = tid & 63, w = tid >> 6;
    const int row0 = blockIdx.x * 128;
    const int col0 = blockIdx.y * 128;

    floatx4 acc[4][4] = {};

    for (int kk = 0; kk < K; kk += 64) {
        __syncthreads();
        // stage A: 1024 16B-slots, linear LDS, lane-linear mapping
        #pragma unroll
        for (int c = 0; c < 4; ++c) {
            int slot = c * 256 + tid;
            int r = slot >> 3, cc = slot & 7;
            const u16* src = A + (size_t)(row0 + r) * K + kk + cc * 8;
            __builtin_amdgcn_global_load_lds(
                (__attribute__((address_space(1))) void*)src,
                (__attribute__((address_space(3))) void*)(As + (size_t)(c * 256 + w * 64) * 8),
                16, 0, 0);
        }
        #pragma unroll
        for (int c = 0; c < 4; ++c) {
            int slot = c * 256 + tid;
            int r = slot >> 3, cc = slot & 7;
            const u16* src = W + (size_t)(col0 + r) * K + kk + cc * 8;
            __builtin_amdgcn_global_load_lds(
                (__attribute__((address_space(1))) void*)src,
                (__attribute__((address_space(3))) void*)(Bs + (size_t)(c * 256 + w * 64) * 8),
                16, 0, 0);
        }
        __syncthreads();

        const int wr = (w >> 1) * 64, wc = (w & 1) * 64;
        #pragma unroll
        for (int ks = 0; ks < 2; ++ks) {
            short8 a[4], b[4];
            #pragma unroll
            for (int mf = 0; mf < 4; ++mf)
                a[mf] = *(const short8*)(As + (wr + mf * 16 + (l & 15)) * 64 + ks * 32 + (l >> 4) * 8);
            #pragma unroll
            for (int nf = 0; nf < 4; ++nf)
                b[nf] = *(const short8*)(Bs + (wc + nf * 16 + (l & 15)) * 64 + ks * 32 + (l >> 4) * 8);
            #pragma unroll
            for (int mf = 0; mf < 4; ++mf)
                #pragma unroll
                for (int nf = 0; nf < 4; ++nf)
                    acc[mf][nf] = __builtin_amdgcn_mfma_f32_16x16x32_bf16(a[mf], b[nf], acc[mf][nf], 0, 0, 0);
        }
    }

    const int wr = (w >> 1) * 64, wc = (w & 1) * 64;
    const int N = (int)gridDim.y * 128;
    float biasv[4];
    #pragma unroll
    for (int nf = 0; nf < 4; ++nf) biasv[nf] = bias[col0 + wc + nf * 16 + (l & 15)];
    #pragma unroll
    for (int mf = 0; mf < 4; ++mf) {
        #pragma unroll
        for (int i = 0; i < 4; ++i) {
            int row = row0 + wr + mf * 16 + ((l >> 4) << 2) + i;
            size_t base = (size_t)row * N;
            #pragma unroll
            for (int nf = 0; nf < 4; ++nf) {
                int col = col0 + wc + nf * 16 + (l & 15);
                float v = acc[mf][nf][i] + biasv[nf];
                if (EPI == 0) {
                    v = 0.5f * v * (1.0f + erff(v * 0.70710678118654752f));
                } else if (EPI == 1) {
                    v += residf[base + col];
                } else {
                    v += bf2f(residb[base + col]);
                }
                out[base + col] = f2bf(v);
            }
        }
    }
}

// ---------------- LayerNorm over E=512, one row per wave ----------------
// OUTF32==0: in-place bf16 -> bf16.  OUTF32==1: bf16 -> fp32 (outf).
template <int OUTF32>
__global__ __launch_bounds__(256) void ln_kernel(u16* __restrict__ x,
                                                 const float* __restrict__ g,
                                                 const float* __restrict__ b,
                                                 float* __restrict__ outf) {
    const int wid = blockIdx.x * 4 + (threadIdx.x >> 6);
    const int l = threadIdx.x & 63;
    uint4* rowp = (uint4*)(x + (size_t)wid * 512);
    uint4 dv = rowp[l];
    u16* p = (u16*)&dv;
    float v[8];
    float s = 0.f, sq = 0.f;
    #pragma unroll
    for (int i = 0; i < 8; ++i) { v[i] = bf2f(p[i]); s += v[i]; sq += v[i] * v[i]; }
    #pragma unroll
    for (int off = 32; off >= 1; off >>= 1) { s += __shfl_xor(s, off); sq += __shfl_xor(sq, off); }
    float mean = s * (1.0f / 512.0f);
    float rstd = rsqrtf(sq * (1.0f / 512.0f) - mean * mean + 1e-5f);
    float gv[8], bv[8];
    *(float4*)&gv[0] = ((const float4*)g)[l * 2];
    *(float4*)&gv[4] = ((const float4*)g)[l * 2 + 1];
    *(float4*)&bv[0] = ((const float4*)b)[l * 2];
    *(float4*)&bv[4] = ((const float4*)b)[l * 2 + 1];
    float o[8];
    #pragma unroll
    for (int i = 0; i < 8; ++i) o[i] = (v[i] - mean) * rstd * gv[i] + bv[i];
    if (OUTF32) {
        float4* op = (float4*)(outf + (size_t)wid * 512);
        float4 o0, o1;
        o0.x = o[0]; o0.y = o[1]; o0.z = o[2]; o0.w = o[3];
        o1.x = o[4]; o1.y = o[5]; o1.z = o[6]; o1.w = o[7];
        op[l * 2] = o0; op[l * 2 + 1] = o1;
    } else {
        #pragma unroll
        for (int i = 0; i < 8; ++i) p[i] = f2bf(o[i]);
        rowp[l] = dv;
    }
}

extern "C" void kernel_launch(void* const* d_in, const int* in_sizes, int n_in,
                              void* d_out, int out_size, void* d_ws, size_t ws_size,
                              hipStream_t stream) {
    const float* text = (const float*)d_in[0];
    const float* img  = (const float*)d_in[1];
    const float* i2t_Wv = (const float*)d_in[4];
    const float* i2t_Wo = (const float*)d_in[5];
    const float* i2t_bv = (const float*)d_in[8];
    const float* i2t_bo = (const float*)d_in[9];
    const float* t2i_Wv = (const float*)d_in[12];
    const float* t2i_Wo = (const float*)d_in[13];
    const float* t2i_bv = (const float*)d_in[16];
    const float* t2i_bo = (const float*)d_in[17];
    const float* W1i = (const float*)d_in[18]; const float* b1i = (const float*)d_in[19];
    const float* W2i = (const float*)d_in[20]; const float* b2i = (const float*)d_in[21];
    const float* W1t = (const float*)d_in[22]; const float* b1t = (const float*)d_in[23];
    const float* W2t = (const float*)d_in[24]; const float* b2t = (const float*)d_in[25];
    const float* ln1i_g = (const float*)d_in[26]; const float* ln1i_b = (const float*)d_in[27];
    const float* ln1t_g = (const float*)d_in[28]; const float* ln1t_b = (const float*)d_in[29];
    const float* ln2i_g = (const float*)d_in[30]; const float* ln2i_b = (const float*)d_in[31];
    const float* ln2t_g = (const float*)d_in[32]; const float* ln2t_b = (const float*)d_in[33];

    float* out_text = (float*)d_out;
    float* out_img  = (float*)d_out + (size_t)BROWS * EDIM;

    // workspace layout (~133 MiB)
    char* ws = (char*)d_ws;
    u16* Xt = (u16*)ws;                                   // 64 MiB  (y1/x1/y2 text, in-place)
    u16* Xi = (u16*)(ws + (size_t)67108864);              // 64 MiB  (img)
    u16* Mi2t = (u16*)(ws + (size_t)134217728);           // 512x512 bf16
    u16* Mt2i  = Mi2t + 512 * 512;
    u16* W1i_b = Mt2i + 512 * 512;                        // 1024x512
    u16* W2i_b = W1i_b + 1024 * 512;                      // 512x1024
    u16* W1t_b = W2i_b + 512 * 1024;
    u16* W2t_b = W1t_b + 1024 * 512;
    float* beff_i2t = (float*)(W2t_b + 512 * 1024);
    float* beff_t2i = beff_i2t + 512;

    // d_out text section doubles as scratch: bf16 feature casts, then FFN hidden h.
    // Every scratch byte is written before read inside this launch; LN2 kernels
    // rewrite all of d_out at the end.
    u16* ft_bf = (u16*)d_out;                             // [65536][512] bf16
    u16* fi_bf = ft_bf + (size_t)BROWS * EDIM;
    u16* h     = (u16*)d_out;                             // [65536][1024] bf16

    // 1) casts + weight prep
    cast_kernel<<<2048, 256, 0, stream>>>(text, ft_bf, BROWS * EDIM / 4);
    cast_kernel<<<2048, 256, 0, stream>>>(img,  fi_bf, BROWS * EDIM / 4);
    cast_kernel<<<256, 256, 0, stream>>>(W1i, W1i_b, FFDIM * EDIM / 4);
    cast_kernel<<<256, 256, 0, stream>>>(W2i, W2i_b, FFDIM * EDIM / 4);
    cast_kernel<<<256, 256, 0, stream>>>(W1t, W1t_b, FFDIM * EDIM / 4);
    cast_kernel<<<256, 256, 0, stream>>>(W2t, W2t_b, FFDIM * EDIM / 4);
    prep_attn<<<64, 256, 0, stream>>>(i2t_Wv, i2t_Wo, i2t_bv, i2t_bo, Mi2t, beff_i2t);
    prep_attn<<<64, 256, 0, stream>>>(t2i_Wv, t2i_Wo, t2i_bv, t2i_bo, Mt2i, beff_t2i);

    dim3 blk(256);
    // 2) stage1: y1 = feat + other_feat @ M^T + beff   (softmax over 1 key == 1)
    gemm_bt<1><<<dim3(512, 4), blk, 0, stream>>>(ft_bf, Mi2t, beff_i2t, 512, img,  nullptr, Xi);
    gemm_bt<1><<<dim3(512, 4), blk, 0, stream>>>(fi_bf, Mt2i, beff_t2i, 512, text, nullptr, Xt);
    // 3) LN1 in place -> x1
    ln_kernel<0><<<BROWS / 4, 256, 0, stream>>>(Xi, ln1i_g, ln1i_b, nullptr);
    ln_kernel<0><<<BROWS / 4, 256, 0, stream>>>(Xt, ln1t_g, ln1t_b, nullptr);
    // 4) img FFN + LN2
    gemm_bt<0><<<dim3(512, 8), blk, 0, stream>>>(Xi, W1i_b, b1i, 512, nullptr, nullptr, h);
    gemm_bt<2><<<dim3(512, 4), blk, 0, stream>>>(h, W2i_b, b2i, 1024, nullptr, Xi, Xi);
    ln_kernel<1><<<BROWS / 4, 256, 0, stream>>>(Xi, ln2i_g, ln2i_b, out_img);
    // 5) text FFN + LN2
    gemm_bt<0><<<dim3(512, 8), blk, 0, stream>>>(Xt, W1t_b, b1t, 512, nullptr, nullptr, h);
    gemm_bt<2><<<dim3(512, 4), blk, 0, stream>>>(h, W2t_b, b2t, 1024, nullptr, Xt, Xt);
    ln_kernel<1><<<BROWS / 4, 256, 0, stream>>>(Xt, ln2t_g, ln2t_b, out_text);
}